// Round 6
// baseline (3879.088 us; speedup 1.0000x reference)
//
#include <hip/hip_runtime.h>

typedef unsigned int u32;

#define N_TOK 65536
#define DIM 256
#define NE 4096
#define TM 256
#define TN 256
#define TK 32
#define NET (NE / TN)  // 16 et tiles per block

__device__ __align__(16) float g_enorm[NE];     // np-exact sum(embed^2, axis=0)
__device__ __align__(16) float g_xnorm[N_TOK];  // np-exact sum(x^2, axis=1)
__device__ float g_diffarr[64];                 // diff partial bins

__device__ __forceinline__ float sqr_rn(float v) { return __fmul_rn(v, v); }

// async 16B global->LDS (DMA). LDS dest lane-linear: f = i*512 + tid.
__device__ __forceinline__ void load16_lds(const float* __restrict__ g, float* l) {
    __builtin_amdgcn_global_load_lds(
        (const __attribute__((address_space(1))) void*)g,
        (__attribute__((address_space(3))) void*)l, 16, 0, 0);
}

// NumPy pairwise_sum for a 128-block of squares (bit-exact helper).
__device__ float np_sum128_sq(const float* __restrict__ a) {
    float r[8];
#pragma unroll
    for (int j = 0; j < 8; ++j) r[j] = sqr_rn(a[j]);
    for (int i = 8; i < 128; i += 8)
#pragma unroll
        for (int j = 0; j < 8; ++j) r[j] = __fadd_rn(r[j], sqr_rn(a[i + j]));
    return __fadd_rn(__fadd_rn(__fadd_rn(r[0], r[1]), __fadd_rn(r[2], r[3])),
                     __fadd_rn(__fadd_rn(r[4], r[5]), __fadd_rn(r[6], r[7])));
}

// ---------------- K1a: x row norms ------------------------------------------
__global__ void k_xnorm(const float* __restrict__ x) {
    const int n = blockIdx.x * 256 + threadIdx.x;
    const float* row = x + (size_t)n * DIM;
    g_xnorm[n] = __fadd_rn(np_sum128_sq(row), np_sum128_sq(row + 128));
    if (blockIdx.x == 0 && threadIdx.x < 64) g_diffarr[threadIdx.x] = 0.f;
}

// ---------------- K1b: embed col norms --------------------------------------
__global__ void k_enorm(const float* __restrict__ embed) {
    const int e = blockIdx.x * 256 + threadIdx.x;
    float s = sqr_rn(embed[e]);
    for (int d = 1; d < DIM; ++d) s = __fadd_rn(s, sqr_rn(embed[(size_t)d * NE + e]));
    g_enorm[e] = s;
}

// ---------------- K2: distance GEMM + argmin, bit-matching np float32 --------
// R6: 512 threads (8 waves = 2/SIMD: covers LDS latency that killed R5's
// 1-wave/SIMD run), 256x256 block tile, 8x16 per-thread tile.
// Per g-group(4k): 8 xt + 16 ev ds_read_b128 per 512 FMAs = 0.75 B/FMA
// (vs 1.0 at 8x8) -> LDS pipe demand ~ FMA wall. ev reads at tx*4 spacing
// 2-way (free); xt reads XOR-swizzled (source-pre-swizzled, linear LDS dest
// per m173) -> 4 distinct bank-quads, conflict-free. Double-buffered xs+es
// (128 KB), one barrier per kt-step (implicit vmcnt(0) drains prev stage).
// k-chain per output: kt->g->kk ascending = k 0..255 single fmaf chain (exact);
// epilogue rounding and first-min scan identical to R0-R5.
__global__ __launch_bounds__(512, 2)
void k_argmin(const float* __restrict__ x, const float* __restrict__ embed,
              float* __restrict__ out_ind) {
    __shared__ __align__(16) float xs0[TM * TK];  // 32 KB  (256 rows x 8 f4-slots)
    __shared__ __align__(16) float xs1[TM * TK];  // 32 KB
    __shared__ __align__(16) float es0[TK * TN];  // 32 KB  (32 k x 64 f4-slots)
    __shared__ __align__(16) float es1[TK * TN];  // 32 KB
    const int tid = threadIdx.x;
    const int tx = tid & 15;    // 16 code-lanes; cols tx*4+j + 64*q, q=0..3
    const int ty = tid >> 4;    // 0..31; rows i*32 + ty, i=0..7
    const int ty7 = ty & 7;
    const int n0 = blockIdx.x * TM;

    // stage x k-slab: 2048 f4 slots; slot f: row r=f>>3, phys grp f&7,
    // logical col-group (f&7)^(r&7)  (XOR pre-swizzle at the SOURCE).
#define STAGE_XS(dst, k0)                                                     \
    {                                                                         \
        _Pragma("unroll") for (int i_ = 0; i_ < 4; ++i_) {                    \
            const int f_ = i_ * 512 + tid;                                    \
            const int r_ = f_ >> 3, c_ = (f_ & 7) ^ (r_ & 7);                 \
            load16_lds(x + (size_t)(n0 + r_) * DIM + (k0) + c_ * 4,           \
                       (dst) + f_ * 4);                                       \
        }                                                                     \
    }
    // stage es tile: 2048 f4 slots, linear [32 k][64 f4]
#define STAGE_ES(dst, k0, e0_)                                                \
    {                                                                         \
        _Pragma("unroll") for (int i_ = 0; i_ < 4; ++i_) {                    \
            const int f_ = i_ * 512 + tid;                                    \
            const int r_ = f_ >> 6, c_ = f_ & 63;                             \
            load16_lds(embed + (size_t)((k0) + r_) * NE + (e0_) + c_ * 4,     \
                       (dst) + f_ * 4);                                       \
        }                                                                     \
    }

    STAGE_XS(xs0, 0);
    STAGE_ES(es0, 0, 0);

    float xn[8];
#pragma unroll
    for (int i = 0; i < 8; i++) xn[i] = g_xnorm[n0 + i * 32 + ty];

    float best[8];
    int bidx[8];
#pragma unroll
    for (int i = 0; i < 8; i++) { best[i] = 3.0e38f; bidx[i] = 0; }

#pragma unroll 1
    for (int et = 0; et < NET; ++et) {
        const int e0 = et * TN;
        float acc[8][16];
#pragma unroll
        for (int i = 0; i < 8; i++)
#pragma unroll
            for (int j = 0; j < 16; j++) acc[i][j] = 0.f;

#pragma unroll 1
        for (int kt = 0; kt < DIM / TK; ++kt) {
            __syncthreads();  // drains this step's DMA (issued last step);
                              // guards overwrite of the other buffer
            {                 // stage next step (block-uniform condition)
                int nkt = kt + 1, net = et;
                if (nkt == 8) { nkt = 0; net = et + 1; }
                if (net < NET) {
                    if (kt & 1) {
                        STAGE_XS(xs0, nkt * TK);
                        STAGE_ES(es0, nkt * TK, net * TN);
                    } else {
                        STAGE_XS(xs1, nkt * TK);
                        STAGE_ES(es1, nkt * TK, net * TN);
                    }
                }
            }
            const float* __restrict__ xsr = (kt & 1) ? xs1 : xs0;
            const float* __restrict__ esr = (kt & 1) ? es1 : es0;

#pragma unroll 1
            for (int g = 0; g < 8; ++g) {
                float4 xt4[8];
#pragma unroll
                for (int i = 0; i < 8; i++)  // 4 distinct addrs (by ty), swizzled banks
                    xt4[i] = *(const float4*)&xsr[((i * 32 + ty) * 8 + (g ^ ty7)) * 4];
#pragma unroll
                for (int kk = 0; kk < 4; kk++) {  // k ascending: one FMA chain
                    const int kb = (g * 4 + kk) * TN;
                    const float4 e0v = *(const float4*)&esr[kb + tx * 4];
                    const float4 e1v = *(const float4*)&esr[kb + 64 + tx * 4];
                    const float4 e2v = *(const float4*)&esr[kb + 128 + tx * 4];
                    const float4 e3v = *(const float4*)&esr[kb + 192 + tx * 4];
#pragma unroll
                    for (int i = 0; i < 8; i++) {
                        const float xk = kk == 0 ? xt4[i].x
                                       : kk == 1 ? xt4[i].y
                                       : kk == 2 ? xt4[i].z : xt4[i].w;
                        acc[i][0]  = fmaf(xk, e0v.x, acc[i][0]);
                        acc[i][1]  = fmaf(xk, e0v.y, acc[i][1]);
                        acc[i][2]  = fmaf(xk, e0v.z, acc[i][2]);
                        acc[i][3]  = fmaf(xk, e0v.w, acc[i][3]);
                        acc[i][4]  = fmaf(xk, e1v.x, acc[i][4]);
                        acc[i][5]  = fmaf(xk, e1v.y, acc[i][5]);
                        acc[i][6]  = fmaf(xk, e1v.z, acc[i][6]);
                        acc[i][7]  = fmaf(xk, e1v.w, acc[i][7]);
                        acc[i][8]  = fmaf(xk, e2v.x, acc[i][8]);
                        acc[i][9]  = fmaf(xk, e2v.y, acc[i][9]);
                        acc[i][10] = fmaf(xk, e2v.z, acc[i][10]);
                        acc[i][11] = fmaf(xk, e2v.w, acc[i][11]);
                        acc[i][12] = fmaf(xk, e3v.x, acc[i][12]);
                        acc[i][13] = fmaf(xk, e3v.y, acc[i][13]);
                        acc[i][14] = fmaf(xk, e3v.z, acc[i][14]);
                        acc[i][15] = fmaf(xk, e3v.w, acc[i][15]);
                    }
                }
            }
        }

        // epilogue: np ((xnorm - 2*mm) + enorm), fp32-rounded each op;
        // within-thread scan ascending in e: q outer, j inner.
        const float4 en0 = *(const float4*)&g_enorm[e0 + tx * 4];
        const float4 en1 = *(const float4*)&g_enorm[e0 + 64 + tx * 4];
        const float4 en2 = *(const float4*)&g_enorm[e0 + 128 + tx * 4];
        const float4 en3 = *(const float4*)&g_enorm[e0 + 192 + tx * 4];
        const float enj[16] = {en0.x, en0.y, en0.z, en0.w, en1.x, en1.y, en1.z, en1.w,
                               en2.x, en2.y, en2.z, en2.w, en3.x, en3.y, en3.z, en3.w};
#pragma unroll
        for (int i = 0; i < 8; i++) {
#pragma unroll
            for (int jj = 0; jj < 16; jj++) {
                float v = __fadd_rn(__fsub_rn(xn[i], __fmul_rn(2.0f, acc[i][jj])), enj[jj]);
                int e = e0 + (jj >> 2) * 64 + tx * 4 + (jj & 3);
                if (v < best[i]) { best[i] = v; bidx[i] = e; }
            }
        }
    }
    // reduce across the 16 tx lanes per token row; ties -> smaller index
#pragma unroll
    for (int i = 0; i < 8; i++) {
        float b = best[i];
        int bi = bidx[i];
#pragma unroll
        for (int m = 1; m < 16; m <<= 1) {
            float ob = __shfl_xor(b, m, 64);
            int oi = __shfl_xor(bi, m, 64);
            if (ob < b || (ob == b && oi < bi)) { b = ob; bi = oi; }
        }
        if (tx == 0) out_ind[n0 + i * 32 + ty] = (float)bi;
    }
}

// ---------------- K3: gather quantize (fp32) + diff partials -----------------
__global__ void k_gather(const float* __restrict__ x, const float* __restrict__ embed,
                         const float* __restrict__ out_ind, float* __restrict__ outq) {
    const int n = blockIdx.x;
    const int d = threadIdx.x;
    int e = (int)out_ind[n];
    e = e < 0 ? 0 : (e > NE - 1 ? NE - 1 : e);  // OOB-proof
    const float v = embed[(size_t)d * NE + e];
    outq[(size_t)n * DIM + d] = v;
    float sq = v - x[(size_t)n * DIM + d];
    sq *= sq;
#pragma unroll
    for (int m = 1; m < 64; m <<= 1) sq += __shfl_xor(sq, m, 64);
    __shared__ float wsum[4];
    if ((d & 63) == 0) wsum[d >> 6] = sq;
    __syncthreads();
    if (d == 0) atomicAdd(&g_diffarr[n & 63], wsum[0] + wsum[1] + wsum[2] + wsum[3]);
}

// ---------------- K4: publish diff -------------------------------------------
__global__ void k_finish(float* __restrict__ out_diff) {
    float t = 0.f;
    for (int w = 0; w < 64; ++w) t += g_diffarr[w];
    if (threadIdx.x == 0) *out_diff = t * (1.0f / 16777216.0f);
}

extern "C" void kernel_launch(void* const* d_in, const int* in_sizes, int n_in,
                              void* d_out, int out_size, void* d_ws, size_t ws_size,
                              hipStream_t stream) {
    const float* x = (const float*)d_in[0];      // [65536, 256]
    const float* embed = (const float*)d_in[1];  // [256, 4096]
    float* outq = (float*)d_out;                 // quantize
    float* out_diff = outq + 16777216;           // diff scalar
    float* out_ind = outq + 16777217;            // embed_ind (float-coded)

    hipLaunchKernelGGL(k_xnorm, dim3(N_TOK / 256), dim3(256), 0, stream, x);
    hipLaunchKernelGGL(k_enorm, dim3(NE / 256), dim3(256), 0, stream, embed);
    hipLaunchKernelGGL(k_argmin, dim3(N_TOK / TM), dim3(512), 0, stream, x, embed, out_ind);
    hipLaunchKernelGGL(k_gather, dim3(N_TOK), dim3(256), 0, stream, x, embed, out_ind, outq);
    hipLaunchKernelGGL(k_finish, dim3(1), dim3(64), 0, stream, out_diff);
}

// Round 7
// 2996.924 us; speedup vs baseline: 1.2944x; 1.2944x over previous
//
#include <hip/hip_runtime.h>

typedef unsigned int u32;

#define N_TOK 65536
#define DIM 256
#define NE 4096
#define TM 256
#define TN 256
#define TK 32
#define NET (NE / TN)  // 16 et tiles

__device__ __align__(16) float g_enorm[NE];     // np-exact sum(embed^2, axis=0)
__device__ __align__(16) float g_xnorm[N_TOK];  // np-exact sum(x^2, axis=1)
__device__ float g_diffarr[64];                 // diff partial bins

__device__ __forceinline__ float sqr_rn(float v) { return __fmul_rn(v, v); }

// async 16B global->LDS (DMA). LDS dest lane-linear: f = i*1024 + tid.
__device__ __forceinline__ void load16_lds(const float* __restrict__ g, float* l) {
    __builtin_amdgcn_global_load_lds(
        (const __attribute__((address_space(1))) void*)g,
        (__attribute__((address_space(3))) void*)l, 16, 0, 0);
}

// NumPy pairwise_sum for a 128-block of squares (bit-exact helper).
__device__ float np_sum128_sq(const float* __restrict__ a) {
    float r[8];
#pragma unroll
    for (int j = 0; j < 8; ++j) r[j] = sqr_rn(a[j]);
    for (int i = 8; i < 128; i += 8)
#pragma unroll
        for (int j = 0; j < 8; ++j) r[j] = __fadd_rn(r[j], sqr_rn(a[i + j]));
    return __fadd_rn(__fadd_rn(__fadd_rn(r[0], r[1]), __fadd_rn(r[2], r[3])),
                     __fadd_rn(__fadd_rn(r[4], r[5]), __fadd_rn(r[6], r[7])));
}

// ---------------- K1a: x row norms ------------------------------------------
__global__ void k_xnorm(const float* __restrict__ x) {
    const int n = blockIdx.x * 256 + threadIdx.x;
    const float* row = x + (size_t)n * DIM;
    g_xnorm[n] = __fadd_rn(np_sum128_sq(row), np_sum128_sq(row + 128));
    if (blockIdx.x == 0 && threadIdx.x < 64) g_diffarr[threadIdx.x] = 0.f;
}

// ---------------- K1b: embed col norms --------------------------------------
__global__ void k_enorm(const float* __restrict__ embed) {
    const int e = blockIdx.x * 256 + threadIdx.x;
    float s = sqr_rn(embed[e]);
    for (int d = 1; d < DIM; ++d) s = __fadd_rn(s, sqr_rn(embed[(size_t)d * NE + e]));
    g_enorm[e] = s;
}

// ---------------- K2: distance GEMM + argmin, bit-matching np float32 --------
// R7: ONE 1024-thread block per CU (grid 256 = CU count) -> 16 waves co-resident
// = 4 waves/SIMD, the TLP that R0-R6 never had (multi-small-block residency is
// pinned ~2 blocks/CU on this machine; occupancy counter calibrated vs R6).
// 4 waves/SIMD => hard 128-VGPR cap (empirical: launch_bounds 2nd arg behaves
// as min-blocks/CU; (1024,1) -> cap 128). Tile sized for it: 8x8 acc (64) +
// 4-row xt half-blocking (16) + ev (8) + best/bidx (16) ~= 120 regs.
// Thread map: tx=tid&31 (codes tx*4+{0..3}, +128), ty=tid>>5 (rows i*32+ty).
// Within a wave ty spans 2 values -> xt reads 2-way broadcast (free, m136);
// ev reads 32-distinct = 4-way (1.58x, ~3% of FMA time - accepted).
// Double-buffered xs/es staged via global_load_lds right after each barrier;
// next barrier (a full ~16K-cyc compute phase later) drains them - latency
// fully hidden. Numerics: per output k=0..255 ascending single fmaf chain
// (kt->g->kk; ih split leaves each output's chain order untouched), identical
// epilogue rounding and first-min scan order as R0-R6 -> bit-identical argmin.
__global__ __launch_bounds__(1024, 1)
void k_argmin(const float* __restrict__ x, const float* __restrict__ embed,
              float* __restrict__ out_ind) {
    __shared__ __align__(16) float xs0[TM * TK];  // 32 KB [256 rows][32 k]
    __shared__ __align__(16) float xs1[TM * TK];  // 32 KB
    __shared__ __align__(16) float es0[TK * TN];  // 32 KB [32 k][256 codes]
    __shared__ __align__(16) float es1[TK * TN];  // 32 KB
    const int tid = threadIdx.x;
    const int tx = tid & 31;   // 32 code-lanes
    const int ty = tid >> 5;   // 0..31 row-groups
    const int n0 = blockIdx.x * TM;

    // xs stage: 2048 f4 slots; f -> row r=f>>3, k-group c=f&7 (plain layout)
#define STAGE_XS(dst, k0)                                                     \
    {                                                                         \
        _Pragma("unroll") for (int i_ = 0; i_ < 2; ++i_) {                    \
            const int f_ = i_ * 1024 + tid;                                   \
            const int r_ = f_ >> 3, c_ = f_ & 7;                              \
            load16_lds(x + (size_t)(n0 + r_) * DIM + (k0) + c_ * 4,          \
                       (dst) + f_ * 4);                                       \
        }                                                                     \
    }
    // es stage: 2048 f4 slots; f -> k row r=f>>6, code-group c=f&63
#define STAGE_ES(dst, k0, e0_)                                                \
    {                                                                         \
        _Pragma("unroll") for (int i_ = 0; i_ < 2; ++i_) {                    \
            const int f_ = i_ * 1024 + tid;                                   \
            const int r_ = f_ >> 6, c_ = f_ & 63;                             \
            load16_lds(embed + (size_t)((k0) + r_) * NE + (e0_) + c_ * 4,    \
                       (dst) + f_ * 4);                                       \
        }                                                                     \
    }

    STAGE_XS(xs0, 0);
    STAGE_ES(es0, 0, 0);

    float best[8];
    int bidx[8];
#pragma unroll
    for (int i = 0; i < 8; i++) { best[i] = 3.0e38f; bidx[i] = 0; }

#pragma unroll 1
    for (int et = 0; et < NET; ++et) {
        const int e0 = et * TN;
        float acc[8][8];
#pragma unroll
        for (int i = 0; i < 8; i++)
#pragma unroll
            for (int j = 0; j < 8; j++) acc[i][j] = 0.f;

#pragma unroll 1
        for (int kt = 0; kt < DIM / TK; ++kt) {
            __syncthreads();  // drains the DMA staged last phase (full compute
                              // phase ago); guards reuse of the other buffer
            {                 // stage next phase (block-uniform condition)
                int nkt = kt + 1, net = et;
                if (nkt == 8) { nkt = 0; net = et + 1; }
                if (net < NET) {
                    if ((kt & 1) == 0) {
                        STAGE_XS(xs1, nkt * TK);
                        STAGE_ES(es1, nkt * TK, net * TN);
                    } else {
                        STAGE_XS(xs0, nkt * TK);
                        STAGE_ES(es0, nkt * TK, net * TN);
                    }
                }
            }
            const float* __restrict__ xsr = (kt & 1) ? xs1 : xs0;
            const float* __restrict__ esr = (kt & 1) ? es1 : es0;

#pragma unroll 1
            for (int g = 0; g < 8; ++g) {
#pragma unroll
                for (int ih = 0; ih < 2; ++ih) {  // 4-row halves: caps xt regs at 16
                    float4 xt[4];
#pragma unroll
                    for (int i2 = 0; i2 < 4; ++i2)  // 2 distinct addrs/wave: free
                        xt[i2] = *(const float4*)&xsr[((ih * 4 + i2) * 32 + ty) * TK + g * 4];
#pragma unroll
                    for (int kk = 0; kk < 4; ++kk) {  // k ascending: one FMA chain
                        const int kb = (g * 4 + kk) * TN;
                        const float4 ea = *(const float4*)&esr[kb + tx * 4];
                        const float4 eb = *(const float4*)&esr[kb + 128 + tx * 4];
#pragma unroll
                        for (int i2 = 0; i2 < 4; ++i2) {
                            const int i = ih * 4 + i2;
                            const float xk = kk == 0 ? xt[i2].x
                                           : kk == 1 ? xt[i2].y
                                           : kk == 2 ? xt[i2].z : xt[i2].w;
                            acc[i][0] = fmaf(xk, ea.x, acc[i][0]);
                            acc[i][1] = fmaf(xk, ea.y, acc[i][1]);
                            acc[i][2] = fmaf(xk, ea.z, acc[i][2]);
                            acc[i][3] = fmaf(xk, ea.w, acc[i][3]);
                            acc[i][4] = fmaf(xk, eb.x, acc[i][4]);
                            acc[i][5] = fmaf(xk, eb.y, acc[i][5]);
                            acc[i][6] = fmaf(xk, eb.z, acc[i][6]);
                            acc[i][7] = fmaf(xk, eb.w, acc[i][7]);
                        }
                    }
                }
            }
        }

        // epilogue: np ((xnorm - 2*mm) + enorm), each op fp32-rounded;
        // within-thread scan ascending in e: j<4 -> tx*4+j, j>=4 -> 128+tx*4+(j-4)
        const float4 ena = *(const float4*)&g_enorm[e0 + tx * 4];
        const float4 enb = *(const float4*)&g_enorm[e0 + 128 + tx * 4];
        const float enj[8] = {ena.x, ena.y, ena.z, ena.w, enb.x, enb.y, enb.z, enb.w};
#pragma unroll
        for (int i = 0; i < 8; i++) {
            const float xnv = g_xnorm[n0 + i * 32 + ty];  // reload: saves 8 regs
#pragma unroll
            for (int j = 0; j < 8; j++) {
                float v = __fadd_rn(__fsub_rn(xnv, __fmul_rn(2.0f, acc[i][j])), enj[j]);
                int e = e0 + (j >> 2) * 128 + tx * 4 + (j & 3);
                if (v < best[i]) { best[i] = v; bidx[i] = e; }
            }
        }
    }
    // reduce across the 32 tx lanes per token row (xor masks <32 stay within
    // each wave half, which holds one ty); ties -> smaller index (np first-min)
#pragma unroll
    for (int i = 0; i < 8; i++) {
        float b = best[i];
        int bi = bidx[i];
#pragma unroll
        for (int m = 1; m < 32; m <<= 1) {
            float ob = __shfl_xor(b, m, 64);
            int oi = __shfl_xor(bi, m, 64);
            if (ob < b || (ob == b && oi < bi)) { b = ob; bi = oi; }
        }
        if (tx == 0) out_ind[n0 + i * 32 + ty] = (float)bi;
    }
}

// ---------------- K3: gather quantize (fp32) + diff partials -----------------
__global__ void k_gather(const float* __restrict__ x, const float* __restrict__ embed,
                         const float* __restrict__ out_ind, float* __restrict__ outq) {
    const int n = blockIdx.x;
    const int d = threadIdx.x;
    int e = (int)out_ind[n];
    e = e < 0 ? 0 : (e > NE - 1 ? NE - 1 : e);  // OOB-proof
    const float v = embed[(size_t)d * NE + e];
    outq[(size_t)n * DIM + d] = v;
    float sq = v - x[(size_t)n * DIM + d];
    sq *= sq;
#pragma unroll
    for (int m = 1; m < 64; m <<= 1) sq += __shfl_xor(sq, m, 64);
    __shared__ float wsum[4];
    if ((d & 63) == 0) wsum[d >> 6] = sq;
    __syncthreads();
    if (d == 0) atomicAdd(&g_diffarr[n & 63], wsum[0] + wsum[1] + wsum[2] + wsum[3]);
}

// ---------------- K4: publish diff -------------------------------------------
__global__ void k_finish(float* __restrict__ out_diff) {
    float t = 0.f;
    for (int w = 0; w < 64; ++w) t += g_diffarr[w];
    if (threadIdx.x == 0) *out_diff = t * (1.0f / 16777216.0f);
}

extern "C" void kernel_launch(void* const* d_in, const int* in_sizes, int n_in,
                              void* d_out, int out_size, void* d_ws, size_t ws_size,
                              hipStream_t stream) {
    const float* x = (const float*)d_in[0];      // [65536, 256]
    const float* embed = (const float*)d_in[1];  // [256, 4096]
    float* outq = (float*)d_out;                 // quantize
    float* out_diff = outq + 16777216;           // diff scalar
    float* out_ind = outq + 16777217;            // embed_ind (float-coded)

    hipLaunchKernelGGL(k_xnorm, dim3(N_TOK / 256), dim3(256), 0, stream, x);
    hipLaunchKernelGGL(k_enorm, dim3(NE / 256), dim3(256), 0, stream, embed);
    hipLaunchKernelGGL(k_argmin, dim3(N_TOK / TM), dim3(1024), 0, stream, x, embed, out_ind);
    hipLaunchKernelGGL(k_gather, dim3(N_TOK), dim3(256), 0, stream, x, embed, out_ind, outq);
    hipLaunchKernelGGL(k_finish, dim3(1), dim3(64), 0, stream, out_diff);
}

// Round 8
// 2063.162 us; speedup vs baseline: 1.8802x; 1.4526x over previous
//
#include <hip/hip_runtime.h>

typedef unsigned int u32;

#define N_TOK 65536
#define DIM 256
#define NE 4096
#define TM 128
#define TN 256
#define TK 32
#define NET (NE / TN)  // 16 et tiles

__device__ __align__(16) float g_enorm[NE];     // np-exact sum(embed^2, axis=0)
__device__ __align__(16) float g_xnorm[N_TOK];  // np-exact sum(x^2, axis=1)
__device__ float g_diffarr[64];                 // diff partial bins

__device__ __forceinline__ float sqr_rn(float v) { return __fmul_rn(v, v); }

// async 16B global->LDS (DMA). LDS dest lane-linear: f = i*512 + tid.
__device__ __forceinline__ void load16_lds(const float* __restrict__ g, float* l) {
    __builtin_amdgcn_global_load_lds(
        (const __attribute__((address_space(1))) void*)g,
        (__attribute__((address_space(3))) void*)l, 16, 0, 0);
}

// NumPy pairwise_sum for a 128-block of squares (bit-exact helper).
__device__ float np_sum128_sq(const float* __restrict__ a) {
    float r[8];
#pragma unroll
    for (int j = 0; j < 8; ++j) r[j] = sqr_rn(a[j]);
    for (int i = 8; i < 128; i += 8)
#pragma unroll
        for (int j = 0; j < 8; ++j) r[j] = __fadd_rn(r[j], sqr_rn(a[i + j]));
    return __fadd_rn(__fadd_rn(__fadd_rn(r[0], r[1]), __fadd_rn(r[2], r[3])),
                     __fadd_rn(__fadd_rn(r[4], r[5]), __fadd_rn(r[6], r[7])));
}

// ---------------- K1a: x row norms ------------------------------------------
__global__ void k_xnorm(const float* __restrict__ x) {
    const int n = blockIdx.x * 256 + threadIdx.x;
    const float* row = x + (size_t)n * DIM;
    g_xnorm[n] = __fadd_rn(np_sum128_sq(row), np_sum128_sq(row + 128));
    if (blockIdx.x == 0 && threadIdx.x < 64) g_diffarr[threadIdx.x] = 0.f;
}

// ---------------- K1b: embed col norms --------------------------------------
__global__ void k_enorm(const float* __restrict__ embed) {
    const int e = blockIdx.x * 256 + threadIdx.x;
    float s = sqr_rn(embed[e]);
    for (int d = 1; d < DIM; ++d) s = __fadd_rn(s, sqr_rn(embed[(size_t)d * NE + e]));
    g_enorm[e] = s;
}

// ---------------- K2: distance GEMM + argmin, bit-matching np float32 --------
// R8: 512 threads, TM=128 x TN=256, grid 512 = 2 blocks/CU -> 16 waves/CU
// (4/SIMD). Empirical VGPR-cap law on this toolchain: cap = 65536/threads
// (256->256, 512->128, 1024->64 across R2/R5/R6/R7). 512 thr -> cap 128; the
// 8x8 tile + ih-halved xt needs ~116 -> no spill (R7's 1024-thr cap 64 spilled).
// Single-buffered 48 KB LDS so two blocks co-reside; stage via global_load_lds
// (DMA) between two barriers; the stage->drain gap of one block is covered by
// the other block's compute (R2's mechanism at 2x the wave count).
// Numerics: per output k=0..255 ascending single fmaf chain (kt->g->kk);
// epilogue ((xnorm - 2*mm) + enorm) each op fp32-rounded; first-min scan
// ascending in e with index tie-break -> bit-identical argmin to R0-R7.
__global__ __launch_bounds__(512, 2)
void k_argmin(const float* __restrict__ x, const float* __restrict__ embed,
              float* __restrict__ out_ind) {
    __shared__ __align__(16) float xs[TM * TK];  // 16 KB [128 rows][32 k]
    __shared__ __align__(16) float es[TK * TN];  // 32 KB [32 k][256 codes]
    const int tid = threadIdx.x;
    const int tx = tid & 31;   // 32 code-lanes; codes tx*4+{0..3} and 128+tx*4+{0..3}
    const int ty = tid >> 5;   // 0..15; token rows i*16 + ty
    const int n0 = blockIdx.x * TM;

    float best[8];
    int bidx[8];
#pragma unroll
    for (int i = 0; i < 8; i++) { best[i] = 3.0e38f; bidx[i] = 0; }

#pragma unroll 1
    for (int et = 0; et < NET; ++et) {
        const int e0 = et * TN;
        float acc[8][8];
#pragma unroll
        for (int i = 0; i < 8; i++)
#pragma unroll
            for (int j = 0; j < 8; j++) acc[i][j] = 0.f;

#pragma unroll 1
        for (int kt = 0; kt < DIM / TK; ++kt) {
            const int k0 = kt * TK;
            __syncthreads();  // all waves done reading previous tile
            // xs stage: 1024 f4 slots; f -> row r=f>>3, k-group c=f&7
#pragma unroll
            for (int i_ = 0; i_ < 2; ++i_) {
                const int f_ = i_ * 512 + tid;
                const int r_ = f_ >> 3, c_ = f_ & 7;
                load16_lds(x + (size_t)(n0 + r_) * DIM + k0 + c_ * 4, xs + f_ * 4);
            }
            // es stage: 2048 f4 slots; f -> k row r=f>>6, code-group c=f&63
#pragma unroll
            for (int i_ = 0; i_ < 4; ++i_) {
                const int f_ = i_ * 512 + tid;
                const int r_ = f_ >> 6, c_ = f_ & 63;
                load16_lds(embed + (size_t)(k0 + r_) * NE + e0 + c_ * 4, es + f_ * 4);
            }
            __syncthreads();  // implicit vmcnt(0) drain -> DMA data visible

#pragma unroll 1
            for (int g = 0; g < 8; ++g) {
#pragma unroll
                for (int ih = 0; ih < 2; ++ih) {  // 4-row halves: caps xt regs at 16
                    float4 xt[4];
#pragma unroll
                    for (int i2 = 0; i2 < 4; ++i2)  // 2 distinct addrs/wave: free bcast
                        xt[i2] = *(const float4*)&xs[((ih * 4 + i2) * 16 + ty) * TK + g * 4];
#pragma unroll
                    for (int kk = 0; kk < 4; ++kk) {  // k ascending: one FMA chain
                        const int kb = (g * 4 + kk) * TN;
                        const float4 ea = *(const float4*)&es[kb + tx * 4];
                        const float4 eb = *(const float4*)&es[kb + 128 + tx * 4];
#pragma unroll
                        for (int i2 = 0; i2 < 4; ++i2) {
                            const int i = ih * 4 + i2;
                            const float xk = kk == 0 ? xt[i2].x
                                           : kk == 1 ? xt[i2].y
                                           : kk == 2 ? xt[i2].z : xt[i2].w;
                            acc[i][0] = fmaf(xk, ea.x, acc[i][0]);
                            acc[i][1] = fmaf(xk, ea.y, acc[i][1]);
                            acc[i][2] = fmaf(xk, ea.z, acc[i][2]);
                            acc[i][3] = fmaf(xk, ea.w, acc[i][3]);
                            acc[i][4] = fmaf(xk, eb.x, acc[i][4]);
                            acc[i][5] = fmaf(xk, eb.y, acc[i][5]);
                            acc[i][6] = fmaf(xk, eb.z, acc[i][6]);
                            acc[i][7] = fmaf(xk, eb.w, acc[i][7]);
                        }
                    }
                }
            }
        }

        // epilogue: np ((xnorm - 2*mm) + enorm), each op fp32-rounded;
        // within-thread scan ascending in e: j<4 -> tx*4+j, j>=4 -> 128+tx*4+(j-4)
        const float4 ena = *(const float4*)&g_enorm[e0 + tx * 4];
        const float4 enb = *(const float4*)&g_enorm[e0 + 128 + tx * 4];
        const float enj[8] = {ena.x, ena.y, ena.z, ena.w, enb.x, enb.y, enb.z, enb.w};
#pragma unroll
        for (int i = 0; i < 8; i++) {
            const float xnv = g_xnorm[n0 + i * 16 + ty];  // reload: saves 8 regs
#pragma unroll
            for (int j = 0; j < 8; j++) {
                float v = __fadd_rn(__fsub_rn(xnv, __fmul_rn(2.0f, acc[i][j])), enj[j]);
                int e = e0 + (j >> 2) * 128 + tx * 4 + (j & 3);
                if (v < best[i]) { best[i] = v; bidx[i] = e; }
            }
        }
    }
    // reduce across the 32 tx lanes per token row (masks 1..16 stay within each
    // wave half = one ty); ties -> smaller index (np first-min)
#pragma unroll
    for (int i = 0; i < 8; i++) {
        float b = best[i];
        int bi = bidx[i];
#pragma unroll
        for (int m = 1; m < 32; m <<= 1) {
            float ob = __shfl_xor(b, m, 64);
            int oi = __shfl_xor(bi, m, 64);
            if (ob < b || (ob == b && oi < bi)) { b = ob; bi = oi; }
        }
        if (tx == 0) out_ind[n0 + i * 16 + ty] = (float)bi;
    }
}

// ---------------- K3: gather quantize (fp32) + diff partials -----------------
__global__ void k_gather(const float* __restrict__ x, const float* __restrict__ embed,
                         const float* __restrict__ out_ind, float* __restrict__ outq) {
    const int n = blockIdx.x;
    const int d = threadIdx.x;
    int e = (int)out_ind[n];
    e = e < 0 ? 0 : (e > NE - 1 ? NE - 1 : e);  // OOB-proof
    const float v = embed[(size_t)d * NE + e];
    outq[(size_t)n * DIM + d] = v;
    float sq = v - x[(size_t)n * DIM + d];
    sq *= sq;
#pragma unroll
    for (int m = 1; m < 64; m <<= 1) sq += __shfl_xor(sq, m, 64);
    __shared__ float wsum[4];
    if ((d & 63) == 0) wsum[d >> 6] = sq;
    __syncthreads();
    if (d == 0) atomicAdd(&g_diffarr[n & 63], wsum[0] + wsum[1] + wsum[2] + wsum[3]);
}

// ---------------- K4: publish diff -------------------------------------------
__global__ void k_finish(float* __restrict__ out_diff) {
    float t = 0.f;
    for (int w = 0; w < 64; ++w) t += g_diffarr[w];
    if (threadIdx.x == 0) *out_diff = t * (1.0f / 16777216.0f);
}

extern "C" void kernel_launch(void* const* d_in, const int* in_sizes, int n_in,
                              void* d_out, int out_size, void* d_ws, size_t ws_size,
                              hipStream_t stream) {
    const float* x = (const float*)d_in[0];      // [65536, 256]
    const float* embed = (const float*)d_in[1];  // [256, 4096]
    float* outq = (float*)d_out;                 // quantize
    float* out_diff = outq + 16777216;           // diff scalar
    float* out_ind = outq + 16777217;            // embed_ind (float-coded)

    hipLaunchKernelGGL(k_xnorm, dim3(N_TOK / 256), dim3(256), 0, stream, x);
    hipLaunchKernelGGL(k_enorm, dim3(NE / 256), dim3(256), 0, stream, embed);
    hipLaunchKernelGGL(k_argmin, dim3(N_TOK / TM), dim3(512), 0, stream, x, embed, out_ind);
    hipLaunchKernelGGL(k_gather, dim3(N_TOK), dim3(256), 0, stream, x, embed, out_ind, outq);
    hipLaunchKernelGGL(k_finish, dim3(1), dim3(64), 0, stream, out_diff);
}